// Round 9
// baseline (67.657 us; speedup 1.0000x reference)
//
#include <hip/hip_runtime.h>

// Bahdanau attention. query [8][400][256], y [8][400][256], Wq_w [128][256],
// Wq_b [128], Wy_w [128][256], Wy_b [128], v_w [1][128], v_b (dropped:
// softmax shift-invariant), n_wins_y [8] i32. out [8][400][256] f32.
//
// score = sum_a v_a*tanh(qp+yp) ~ const - sum_a 2 v_a/(Eq_a*Ey_a + 1),
// Eq = e^{2 qp}, Ey = e^{2 yp} precomputed -> score inner loop has NO
// transcendentals: a = fma(Eq,Ey,1) per elem + 1 rcp per 4 (recip-of-product).
//
// K0 transpose: WT4[k4][a] so proj W-loads are coalesced (R7: scattered-W
//    proj was ~17us; fix measured -9.4us).
// K1 proj: Eq/Ey. 800 blocks x 256 (8 rows, k-halves, LDS reduce).
// K2 fused score+softmax+apply (one launch, no s round-trip):
//    - 400 blocks (b x 50 qgroups of 8), 512 thr, wave=q in score/softmax.
//    - score: stride-65 transposed Ey tiles (0-conflict, verified), named
//      prefetch regs (R4 lesson: no runtime-indexed register arrays -> no
//      scratch), constant-trip guarded loop, early-exit at ceil(n/64).
//    - apply: lane=(q,d4i), wave=d4-octet: y-tile reads are 128B contiguous
//      8-way-broadcast (conflict-free); s_p stride 409 (25 mod 32, 8 distinct
//      banks); 16-t double-buffered tiles, 1 barrier/tile (invariant safe:
//      write(i) is post-SYNC(i-1) which is post-all-waves' compute(i-2)).

#define LOG2E 1.4426950408889634f
#define TANH_SCALE 2.8853900817779268f  // 2*log2(e)

constexpr int TQn = 400, TYn = 400, AD = 128, DD = 256;
constexpr int QT = 8;               // q per fused block (1 wave each)
constexpr int QBLOCKS = TQn / QT;   // 50
constexpr int SSTR = 65;            // Ey^T tile stride (float4)
constexpr int PSTR = 409;           // s_p row stride (floats), 409%32=25

// ---------------- K0: WT4[k4][a] = W[a][4k4..4k4+3] ------------------------
__global__ __launch_bounds__(128) void transpose_kernel(
    const float* __restrict__ Wq, const float* __restrict__ Wy,
    float4* __restrict__ WTq, float4* __restrict__ WTy)
{
    const int k4 = blockIdx.x & 63;
    const bool isq = blockIdx.x < 64;
    const float4* src = reinterpret_cast<const float4*>(isq ? Wq : Wy);
    float4* dst = isq ? WTq : WTy;
    const int a = threadIdx.x;                 // 0..127
    dst[k4 * 128 + a] = src[a * 64 + k4];
}

// ---------------- K1: Eq = exp(2(Wq q + b)); Ey likewise -------------------
__global__ __launch_bounds__(256, 4) void proj_kernel(
    const float* __restrict__ qin, const float* __restrict__ yin,
    const float4* __restrict__ WTq, const float* __restrict__ bq,
    const float4* __restrict__ WTy, const float* __restrict__ by,
    float* __restrict__ Eq, float* __restrict__ Ey)
{
    const int blk = blockIdx.x;               // [0,400) q, [400,800) y
    const bool is_q = blk < 400;
    const int row0 = (is_q ? blk : blk - 400) * 8;
    const float* in   = (is_q ? qin : yin) + (size_t)row0 * DD;
    const float4* wt  = is_q ? WTq : WTy;     // [64 k4][128 a]
    const float* bias = is_q ? bq : by;
    float* outp = (is_q ? Eq : Ey) + (size_t)row0 * AD;

    __shared__ float lin[8 * DD];             // 8 KB
    __shared__ float red[8][AD];              // 4 KB
    {
        const float4* in4 = reinterpret_cast<const float4*>(in);
        float4* l4s = reinterpret_cast<float4*>(lin);
        l4s[threadIdx.x]       = in4[threadIdx.x];
        l4s[threadIdx.x + 256] = in4[threadIdx.x + 256];
    }
    __syncthreads();

    const int a = threadIdx.x & 127;
    const int h = threadIdx.x >> 7;           // k-half
    float acc[8] = {0.f,0.f,0.f,0.f,0.f,0.f,0.f,0.f};
    const float4* l4 = reinterpret_cast<const float4*>(lin);
    #pragma unroll 8
    for (int i = 0; i < 32; ++i) {
        const int k4 = h * 32 + i;
        float4 w4 = wt[k4 * 128 + a];         // coalesced 16B/lane
        #pragma unroll
        for (int r = 0; r < 8; ++r) {
            float4 v = l4[r * 64 + k4];       // uniform broadcast
            acc[r] = fmaf(w4.x, v.x, acc[r]);
            acc[r] = fmaf(w4.y, v.y, acc[r]);
            acc[r] = fmaf(w4.z, v.z, acc[r]);
            acc[r] = fmaf(w4.w, v.w, acc[r]);
        }
    }
    if (h) {
        #pragma unroll
        for (int r = 0; r < 8; ++r) red[r][a] = acc[r];
    }
    __syncthreads();
    if (!h) {
        const float bb = bias[a];
        #pragma unroll
        for (int r = 0; r < 8; ++r)
            outp[(size_t)r * AD + a] =
                __builtin_amdgcn_exp2f((acc[r] + red[r][a] + bb) * TANH_SCALE);
    }
}

// ---------------- K2: fused scores -> softmax -> att@y ---------------------
__global__ __launch_bounds__(512, 4) void fused_kernel(
    const float* __restrict__ y,    // [B][TY][DD]
    const float* __restrict__ Eq,   // [B*TQ][AD]
    const float* __restrict__ Ey,   // [B*TY][AD]
    const float* __restrict__ vw,   // [AD]
    const int*  __restrict__ nwins, // [B]
    float* __restrict__ out)        // [B][TQ][DD]
{
    __shared__ float4 s_eq4[QT * 32];     // 4 KB
    __shared__ float4 s_v4[32];           // 0.5 KB (-2v)
    __shared__ float4 s_big[32 * SSTR];   // 33.3 KB: Ey^T tile / y dbuf (2x1024)
    __shared__ float  s_p[QT][PSTR];      // 13.1 KB

    const int b  = blockIdx.x / QBLOCKS;
    const int q0 = (blockIdx.x % QBLOCKS) * QT;
    const int tid = threadIdx.x;          // 0..511
    const int wave = tid >> 6;            // score/softmax: local q
    const int lane = tid & 63;
    const int n = nwins[b];
    const float NEG_INF = -__builtin_inff();

    const float4* eyb = reinterpret_cast<const float4*>(Ey);
    const float4* yb  = reinterpret_cast<const float4*>(y) + (size_t)(b * TYn) * 64;

    // score staging coords
    const int pcol = tid & 31;            // a4
    const int prow = tid >> 5;            // 0..15

    // named prefetch registers (R4 lesson: never an indexable array)
    float4 p0, p1, p2, p3;
    {   // score tile 0 (rows 0..63 valid: n >= 200)
        const size_t base = (size_t)(b * TYn) * 32 + pcol;
        p0 = eyb[base + (size_t)(prow +  0) * 32];
        p1 = eyb[base + (size_t)(prow + 16) * 32];
        p2 = eyb[base + (size_t)(prow + 32) * 32];
        p3 = eyb[base + (size_t)(prow + 48) * 32];
    }
    if (tid < QT * 32) {
        s_eq4[tid] = reinterpret_cast<const float4*>(Eq + (size_t)(b * TQn + q0) * AD)[tid];
    } else if (tid < QT * 32 + 32) {
        float4 v = reinterpret_cast<const float4*>(vw)[tid - QT * 32];
        s_v4[tid - QT * 32] = make_float4(-2.f * v.x, -2.f * v.y, -2.f * v.z, -2.f * v.w);
    }

    float sc[7];
    #pragma unroll
    for (int j = 0; j < 7; ++j) sc[j] = NEG_INF;
    const int ntile = (n + 63) >> 6;      // 4..7, block-uniform

    // ---- score: constant-trip, uniform guard; 2 barriers/tile (R4 proven) ----
    #pragma unroll
    for (int i = 0; i < 7; ++i) {
        if (i < ntile) {
            __syncthreads();  // prior tile's reads done (covers eq/v on i==0)
            s_big[pcol * SSTR + prow +  0] = p0;  // transposed store
            s_big[pcol * SSTR + prow + 16] = p1;
            s_big[pcol * SSTR + prow + 32] = p2;
            s_big[pcol * SSTR + prow + 48] = p3;
            if (i + 1 < ntile) {
                const int t0n = (i + 1) * 64;
                const size_t base = (size_t)(b * TYn) * 32 + pcol;
                int r0 = min(t0n + prow +  0, TYn - 1);
                int r1 = min(t0n + prow + 16, TYn - 1);
                int r2 = min(t0n + prow + 32, TYn - 1);
                int r3 = min(t0n + prow + 48, TYn - 1);
                p0 = eyb[base + (size_t)r0 * 32];  // in flight over compute
                p1 = eyb[base + (size_t)r1 * 32];
                p2 = eyb[base + (size_t)r2 * 32];
                p3 = eyb[base + (size_t)r3 * 32];
            }
            __syncthreads();
            float ac0 = 0.f, ac1 = 0.f, ac2 = 0.f, ac3 = 0.f;
            const float4* qrow = s_eq4 + wave * 32;
            #pragma unroll 8
            for (int a4 = 0; a4 < 32; ++a4) {
                float4 yv = s_big[a4 * SSTR + lane];  // contiguous 64-lane sweep
                float4 qv = qrow[a4];                 // wave-uniform broadcast
                float4 vv = s_v4[a4];                 // broadcast (-2v)
                float a0 = fmaf(qv.x, yv.x, 1.f);
                float a1 = fmaf(qv.y, yv.y, 1.f);
                float a2 = fmaf(qv.z, yv.z, 1.f);
                float a3 = fmaf(qv.w, yv.w, 1.f);
                float p01 = a0 * a1, p23 = a2 * a3;
                float R = __builtin_amdgcn_rcpf(p01 * p23);
                float u = p23 * R, w = p01 * R;       // u=1/p01, w=1/p23
                ac0 = fmaf(vv.x, a1 * u, ac0);
                ac1 = fmaf(vv.y, a0 * u, ac1);
                ac2 = fmaf(vv.z, a3 * w, ac2);
                ac3 = fmaf(vv.w, a2 * w, ac3);
            }
            sc[i] = (ac0 + ac1) + (ac2 + ac3);  // garbage rows masked below
        }
    }
    __syncthreads();  // ALL waves done reading s_big before apply reuses it

    // apply tile-0 prefetch (rows 0..15 valid); overlaps softmax
    const int scol = tid & 63, srow0 = tid >> 6;
    float4 g0 = yb[(size_t)(srow0    ) * 64 + scol];
    float4 g1 = yb[(size_t)(srow0 + 8) * 64 + scol];

    // ---- softmax over t for q = q0 + wave ----
    #pragma unroll
    for (int j = 0; j < 7; ++j) {
        int t = j * 64 + lane;
        if (t >= n) sc[j] = NEG_INF;
    }
    float m = sc[0];
    #pragma unroll
    for (int j = 1; j < 7; ++j) m = fmaxf(m, sc[j]);
    #pragma unroll
    for (int off = 32; off >= 1; off >>= 1) m = fmaxf(m, __shfl_xor(m, off, 64));
    float l = 0.f;
    #pragma unroll
    for (int j = 0; j < 7; ++j) {
        float pv = __builtin_amdgcn_exp2f((sc[j] - m) * LOG2E);  // exp2(-inf)=0
        sc[j] = pv;
        l += pv;
    }
    #pragma unroll
    for (int off = 32; off >= 1; off >>= 1) l += __shfl_xor(l, off, 64);
    const float inv = 1.0f / l;
    #pragma unroll
    for (int j = 0; j < 7; ++j) {
        const int t = j * 64 + lane;
        if (t < TYn) s_p[wave][t] = sc[j] * inv;  // 0 beyond n; t>=400 dropped
    }

    // ---- apply: lane=(q,d4i), wave=d4-octet; dbuf halves of s_big ----
    const int q  = lane >> 3;                  // 0..7
    const int d4 = (wave << 3) | (lane & 7);   // 0..63
    float4 acc = {0.f, 0.f, 0.f, 0.f};
    const int nta = (n + 15) >> 4;             // 13..25, block-uniform
    for (int i = 0; i < nta; ++i) {
        float4* buf = s_big + (i & 1) * 1024;  // 16x64 f4
        buf[(srow0    ) * 64 + scol] = g0;
        buf[(srow0 + 8) * 64 + scol] = g1;
        if (i + 1 < nta) {
            const int t0n = (i + 1) * 16;      // rows <= 399 guaranteed
            g0 = yb[(size_t)(t0n + srow0    ) * 64 + scol];
            g1 = yb[(size_t)(t0n + srow0 + 8) * 64 + scol];
        }
        __syncthreads();  // buf ready; s_p visible (i==0); dbuf invariant safe
        const int tb = i * 16;
        #pragma unroll
        for (int ttl = 0; ttl < 16; ++ttl) {
            const float  pt = s_p[q][tb + ttl];   // 8 distinct banks, 8-way bcast
            const float4 yv = buf[ttl * 64 + d4]; // 128B contiguous, 8-way bcast
            acc.x = fmaf(pt, yv.x, acc.x);
            acc.y = fmaf(pt, yv.y, acc.y);
            acc.z = fmaf(pt, yv.z, acc.z);
            acc.w = fmaf(pt, yv.w, acc.w);
        }
    }
    reinterpret_cast<float4*>(out)[(size_t)(b * TQn + q0 + q) * 64 + d4] = acc;
}

extern "C" void kernel_launch(void* const* d_in, const int* in_sizes, int n_in,
                              void* d_out, int out_size, void* d_ws, size_t ws_size,
                              hipStream_t stream) {
    const float* query = (const float*)d_in[0];
    const float* y     = (const float*)d_in[1];
    const float* Wq_w  = (const float*)d_in[2];
    const float* Wq_b  = (const float*)d_in[3];
    const float* Wy_w  = (const float*)d_in[4];
    const float* Wy_b  = (const float*)d_in[5];
    const float* v_w   = (const float*)d_in[6];
    // d_in[7] = v_b: softmax-invariant, dropped.
    const int* nw      = (const int*)d_in[8];
    float* out = (float*)d_out;

    float4* WTq = (float4*)d_ws;                   // 131 KB
    float4* WTy = WTq + 64 * 128;                  // 131 KB
    float*  Eq  = (float*)(WTy + 64 * 128);        // [3200][128] = 1.64 MB
    float*  Ey  = Eq + (size_t)8 * TQn * AD;       // 1.64 MB

    transpose_kernel<<<128, 128, 0, stream>>>(Wq_w, Wy_w, WTq, WTy);
    proj_kernel<<<800, 256, 0, stream>>>(query, y, WTq, Wq_b, WTy, Wy_b, Eq, Ey);
    fused_kernel<<<8 * QBLOCKS, 512, 0, stream>>>(y, Eq, Ey, v_w, nw, out);
}